// Round 1
// baseline (933.724 us; speedup 1.0000x reference)
//
#include <hip/hip_runtime.h>
#include <hip/hip_bf16.h>
#include <math.h>

// GNN_5480378269924: 3-layer GCN + BN + GELU + residual + meanpool + MLP -> scalar.
// Strategy: device-built CSR (deterministic gather aggregation), fp32 GEMMs with
// LDS-staged W, double-precision BN stats / pooling, fused epilogues.

#define WS_ALIGN 16

__device__ __forceinline__ float gelu_f(float x) {
    // exact erf GELU (matches jax.nn.gelu approximate=False)
    return 0.5f * x * (1.0f + erff(x * 0.7071067811865476f));
}

__device__ __forceinline__ int wave_incl_scan(int v, int lane) {
#pragma unroll
    for (int off = 1; off < 64; off <<= 1) {
        int t = __shfl_up(v, (unsigned)off, 64);
        if (lane >= off) v += t;
    }
    return v;
}

// ---- init: deg = 1.0 (self loop), zero double accumulators ----
__global__ void init_kernel(float* __restrict__ deg, double* __restrict__ dbls,
                            int n, int ndbl) {
    int i = blockIdx.x * 256 + threadIdx.x;
    if (i < n) deg[i] = 1.0f;
    if (i < ndbl) dbls[i] = 0.0;
}

// ---- degree count over edge targets ----
__global__ void degree_kernel(const int* __restrict__ col, float* __restrict__ deg, int E) {
    int e = blockIdx.x * 256 + threadIdx.x;
    if (e < E) atomicAdd(&deg[col[e]], 1.0f);
}

// ---- scan pass 1: per-block exclusive scan of cnt=(deg-1), also dinv ----
__global__ __launch_bounds__(256) void scan1_kernel(const float* __restrict__ deg,
                                                    float* __restrict__ dinv,
                                                    int* __restrict__ offs,
                                                    int* __restrict__ bsums, int n) {
    int i = blockIdx.x * 256 + threadIdx.x;
    int lane = threadIdx.x & 63;
    int wid = threadIdx.x >> 6;
    int cnt = 0;
    if (i < n) {
        float d = deg[i];
        dinv[i] = 1.0f / sqrtf(d);
        cnt = (int)d - 1;
    }
    int incl = wave_incl_scan(cnt, lane);
    __shared__ int ws[4];
    if (lane == 63) ws[wid] = incl;
    __syncthreads();
    if (threadIdx.x == 0) {
        int a = 0;
#pragma unroll
        for (int j = 0; j < 4; j++) { int t = ws[j]; ws[j] = a; a += t; }
        bsums[blockIdx.x] = a;
    }
    __syncthreads();
    int excl = incl - cnt + ws[wid];
    if (i < n) offs[i] = excl;
}

// ---- scan pass 2: single block scans block sums (nblk <= 512) ----
__global__ __launch_bounds__(512) void scan2_kernel(int* __restrict__ bsums, int nblk) {
    int lane = threadIdx.x & 63;
    int wid = threadIdx.x >> 6;
    int v = (threadIdx.x < nblk) ? bsums[threadIdx.x] : 0;
    int incl = wave_incl_scan(v, lane);
    __shared__ int ws[8];
    if (lane == 63) ws[wid] = incl;
    __syncthreads();
    if (threadIdx.x == 0) {
        int a = 0;
#pragma unroll
        for (int j = 0; j < 8; j++) { int t = ws[j]; ws[j] = a; a += t; }
    }
    __syncthreads();
    int excl = incl - v + ws[wid];
    if (threadIdx.x < nblk) bsums[threadIdx.x] = excl;
}

// ---- scan pass 3: add block bases; init fill cursors ----
__global__ void scan3_kernel(int* __restrict__ offs, const int* __restrict__ bsums,
                             int* __restrict__ cursor, int n) {
    int i = blockIdx.x * 256 + threadIdx.x;
    if (i < n) {
        int o = offs[i] + bsums[i >> 8];
        offs[i] = o;
        cursor[i] = o;
    }
}

// ---- CSR fill: csr[pos] = src row for each in-edge of col ----
__global__ void fill_kernel(const int* __restrict__ row, const int* __restrict__ col,
                            int* __restrict__ cursor, int* __restrict__ csr, int E) {
    int e = blockIdx.x * 256 + threadIdx.x;
    if (e < E) {
        int c = col[e];
        int pos = atomicAdd(&cursor[c], 1);
        csr[pos] = row[e];
    }
}

// ---- GEMM: U[n][DOUT] = (H[n][DIN] @ W) * dinv[n] ----
template <int DIN, int DOUT>
__global__ __launch_bounds__(256) void gemm_kernel(const float* __restrict__ H,
                                                   const float* __restrict__ W,
                                                   const float* __restrict__ dinv,
                                                   float* __restrict__ U, int n) {
    constexpr int KT = 64;
    constexpr int GPN = DOUT / 4;   // threads covering one node's outputs
    constexpr int NG = 256 / GPN;   // node-groups per block
    constexpr int NT = 4;           // nodes per thread
    __shared__ float Ws[KT * DOUT];

    int g = threadIdx.x / GPN;
    int cl = threadIdx.x % GPN;
    int c4 = cl * 4;
    int node0 = (blockIdx.x * NG + g) * NT;
    int nv = n - node0;
    if (nv > NT) nv = NT;
    if (nv < 0) nv = 0;

    float4 acc[NT];
#pragma unroll
    for (int j = 0; j < NT; j++) { acc[j].x = acc[j].y = acc[j].z = acc[j].w = 0.0f; }

    for (int kb = 0; kb < DIN; kb += KT) {
        __syncthreads();
        for (int t = threadIdx.x; t < KT * DOUT / 4; t += 256)
            *(float4*)(Ws + t * 4) = *(const float4*)(W + (size_t)kb * DOUT + t * 4);
        __syncthreads();
        if (nv == NT) {
#pragma unroll 4
            for (int k = 0; k < KT; k++) {
                float4 w4 = *(const float4*)(Ws + k * DOUT + c4);
#pragma unroll
                for (int j = 0; j < NT; j++) {
                    float hk = H[(size_t)(node0 + j) * DIN + kb + k];
                    acc[j].x = fmaf(hk, w4.x, acc[j].x);
                    acc[j].y = fmaf(hk, w4.y, acc[j].y);
                    acc[j].z = fmaf(hk, w4.z, acc[j].z);
                    acc[j].w = fmaf(hk, w4.w, acc[j].w);
                }
            }
        } else if (nv > 0) {
            for (int k = 0; k < KT; k++) {
                float4 w4 = *(const float4*)(Ws + k * DOUT + c4);
                for (int j = 0; j < nv; j++) {
                    float hk = H[(size_t)(node0 + j) * DIN + kb + k];
                    acc[j].x = fmaf(hk, w4.x, acc[j].x);
                    acc[j].y = fmaf(hk, w4.y, acc[j].y);
                    acc[j].z = fmaf(hk, w4.z, acc[j].z);
                    acc[j].w = fmaf(hk, w4.w, acc[j].w);
                }
            }
        }
    }
    for (int j = 0; j < nv; j++) {
        float dv = dinv[node0 + j];
        float4 r;
        r.x = acc[j].x * dv; r.y = acc[j].y * dv;
        r.z = acc[j].z * dv; r.w = acc[j].w * dv;
        *(float4*)(U + (size_t)(node0 + j) * DOUT + c4) = r;
    }
}

// ---- aggregation: Out[i] = dinv[i]*(u[i] + sum_{src in-edges} u[src]) + b ----
template <int DOUT>
__global__ __launch_bounds__(256) void agg_kernel(const float* __restrict__ U,
                                                  const int* __restrict__ csr,
                                                  const int* __restrict__ offs,
                                                  const float* __restrict__ deg,
                                                  const float* __restrict__ dinv,
                                                  const float* __restrict__ bias,
                                                  float* __restrict__ Out, int n) {
    constexpr int GPN = DOUT / 4;
    constexpr int NPB = 256 / GPN;
    int g = threadIdx.x / GPN;
    int cl = threadIdx.x % GPN;
    int node = blockIdx.x * NPB + g;
    if (node >= n) return;
    int c4 = cl * 4;

    float4 acc = *(const float4*)(U + (size_t)node * DOUT + c4);  // self loop
    int start = offs[node];
    int cnt = (int)deg[node] - 1;
    for (int j = 0; j < cnt; j++) {
        int src = csr[start + j];
        float4 uv = *(const float4*)(U + (size_t)src * DOUT + c4);
        acc.x += uv.x; acc.y += uv.y; acc.z += uv.z; acc.w += uv.w;
    }
    float dv = dinv[node];
    float4 b4 = *(const float4*)(bias + c4);
    float4 r;
    r.x = fmaf(acc.x, dv, b4.x);
    r.y = fmaf(acc.y, dv, b4.y);
    r.z = fmaf(acc.z, dv, b4.z);
    r.w = fmaf(acc.w, dv, b4.w);
    *(float4*)(Out + (size_t)node * DOUT + c4) = r;
}

// ---- BN stats: per-channel sum and sumsq (double) ----
template <int D>
__global__ __launch_bounds__(256) void stats_kernel(const float* __restrict__ X,
                                                    double* __restrict__ stats, int n) {
    constexpr int RPB = 256 / D;
    int c = threadIdx.x % D;
    int r0 = threadIdx.x / D;
    double s = 0.0, s2 = 0.0;
    int rowsPerGrid = gridDim.x * RPB;
    for (int r = blockIdx.x * RPB + r0; r < n; r += rowsPerGrid) {
        float v = X[(size_t)r * D + c];
        s += v;
        s2 += (double)v * (double)v;
    }
    __shared__ double sh[256];
    __shared__ double sh2[256];
    sh[threadIdx.x] = s;
    sh2[threadIdx.x] = s2;
    __syncthreads();
    if (threadIdx.x < D) {
#pragma unroll
        for (int j = 1; j < RPB; j++) {
            s += sh[threadIdx.x + j * D];
            s2 += sh2[threadIdx.x + j * D];
        }
        atomicAdd(&stats[c], s);
        atomicAdd(&stats[c + D], s2);
    }
}

// ---- BN normalize + GELU in place ----
template <int D>
__global__ __launch_bounds__(256) void norm_kernel(float* __restrict__ X,
                                                   const double* __restrict__ stats,
                                                   const float* __restrict__ gw,
                                                   const float* __restrict__ be, int n) {
    constexpr int RPB = 256 / D;
    int c = threadIdx.x % D;
    double mu = stats[c] / n;
    double var = stats[c + D] / n - mu * mu;
    double inv = 1.0 / sqrt(var + 1e-5);
    float scale = (float)((double)gw[c] * inv);
    float shift = (float)((double)be[c] - mu * (double)gw[c] * inv);
    int r0 = threadIdx.x / D;
    int rowsPerGrid = gridDim.x * RPB;
    for (int r = blockIdx.x * RPB + r0; r < n; r += rowsPerGrid) {
        size_t idx = (size_t)r * D + c;
        float t = fmaf(X[idx], scale, shift);
        X[idx] = gelu_f(t);
    }
}

// ---- layer-3: BN normalize + GELU + residual(x) + mean-pool accumulate ----
__global__ __launch_bounds__(256) void norm_pool_kernel(const float* __restrict__ X3,
                                                        const float* __restrict__ x0,
                                                        const double* __restrict__ stats,
                                                        const float* __restrict__ gw,
                                                        const float* __restrict__ be,
                                                        double* __restrict__ pool, int n) {
    constexpr int D = 64;
    constexpr int RPB = 4;
    int c = threadIdx.x % D;
    double mu = stats[c] / n;
    double var = stats[c + D] / n - mu * mu;
    double inv = 1.0 / sqrt(var + 1e-5);
    float scale = (float)((double)gw[c] * inv);
    float shift = (float)((double)be[c] - mu * (double)gw[c] * inv);
    int r0 = threadIdx.x / D;
    int rowsPerGrid = gridDim.x * RPB;
    double s = 0.0;
    for (int r = blockIdx.x * RPB + r0; r < n; r += rowsPerGrid) {
        size_t idx = (size_t)r * D + c;
        float t = fmaf(X3[idx], scale, shift);
        float res = x0[idx] + gelu_f(t);
        s += res;
    }
    __shared__ double sh[256];
    sh[threadIdx.x] = s;
    __syncthreads();
    if (threadIdx.x < D) {
#pragma unroll
        for (int j = 1; j < RPB; j++) s += sh[threadIdx.x + j * D];
        atomicAdd(&pool[c], s);
    }
}

// ---- head MLP: 64 ->128 ->64 ->32 ->1, single block ----
__global__ __launch_bounds__(128) void mlp_kernel(const double* __restrict__ pool,
                                                  const float* __restrict__ w1, const float* __restrict__ b1,
                                                  const float* __restrict__ w2, const float* __restrict__ b2,
                                                  const float* __restrict__ w3, const float* __restrict__ b3,
                                                  const float* __restrict__ w4, const float* __restrict__ b4,
                                                  float* __restrict__ out, int n) {
    __shared__ float v0[64], h1[128], h2[64], h3[32];
    int t = threadIdx.x;
    if (t < 64) v0[t] = (float)(pool[t] / (double)n);
    __syncthreads();
    if (t < 128) {
        float a = b1[t];
        for (int k = 0; k < 64; k++) a = fmaf(v0[k], w1[k * 128 + t], a);
        h1[t] = gelu_f(a);
    }
    __syncthreads();
    if (t < 64) {
        float a = b2[t];
        for (int k = 0; k < 128; k++) a = fmaf(h1[k], w2[k * 64 + t], a);
        h2[t] = gelu_f(a);
    }
    __syncthreads();
    if (t < 32) {
        float a = b3[t];
        for (int k = 0; k < 64; k++) a = fmaf(h2[k], w3[k * 32 + t], a);
        h3[t] = gelu_f(a);
    }
    __syncthreads();
    if (t == 0) {
        float a = b4[0];
        for (int k = 0; k < 32; k++) a = fmaf(h3[k], w4[k], a);
        out[0] = a;
    }
}

extern "C" void kernel_launch(void* const* d_in, const int* in_sizes, int n_in,
                              void* d_out, int out_size, void* d_ws, size_t ws_size,
                              hipStream_t stream) {
    const float* x    = (const float*)d_in[0];
    const int*   ei   = (const int*)d_in[1];
    const float* W1   = (const float*)d_in[2];
    const float* b1   = (const float*)d_in[3];
    const float* g1   = (const float*)d_in[4];
    const float* be1  = (const float*)d_in[5];
    const float* W2   = (const float*)d_in[6];
    const float* b2   = (const float*)d_in[7];
    const float* g2   = (const float*)d_in[8];
    const float* be2  = (const float*)d_in[9];
    const float* W3   = (const float*)d_in[10];
    const float* b3   = (const float*)d_in[11];
    const float* g3   = (const float*)d_in[12];
    const float* be3  = (const float*)d_in[13];
    const float* fc1w = (const float*)d_in[14];
    const float* fc1b = (const float*)d_in[15];
    const float* fc2w = (const float*)d_in[16];
    const float* fc2b = (const float*)d_in[17];
    const float* fc3w = (const float*)d_in[18];
    const float* fc3b = (const float*)d_in[19];
    const float* fc4w = (const float*)d_in[20];
    const float* fc4b = (const float*)d_in[21];

    const int N = in_sizes[0] / 64;
    const int E = in_sizes[1] / 2;
    const int* e_row = ei;       // source
    const int* e_col = ei + E;   // target (aggregation index)

    // ---- workspace layout ----
    char* ws = (char*)d_ws;
    size_t off = 0;
    double* stats1 = (double*)(ws + off); off += 256 * sizeof(double);
    double* stats2 = (double*)(ws + off); off += 256 * sizeof(double);
    double* stats3 = (double*)(ws + off); off += 256 * sizeof(double);
    double* pool   = (double*)(ws + off); off += 64 * sizeof(double);
    float* deg   = (float*)(ws + off); off += (size_t)N * sizeof(float);
    float* dinv  = (float*)(ws + off); off += (size_t)N * sizeof(float);
    off = (off + 15) & ~(size_t)15;
    int* offs    = (int*)(ws + off); off += (size_t)N * sizeof(int);
    int* cursor  = (int*)(ws + off); off += (size_t)N * sizeof(int);
    int* bsums   = (int*)(ws + off); off += 512 * sizeof(int);
    int* csr     = (int*)(ws + off); off += (size_t)E * sizeof(int);
    off = (off + 15) & ~(size_t)15;
    float* U     = (float*)(ws + off); off += (size_t)N * 128 * sizeof(float);
    float* H     = (float*)(ws + off); off += (size_t)N * 128 * sizeof(float);
    // total ~110.4 MB; assumed <= ws_size

    const int nb256 = (N + 255) / 256;
    const int ebl = (E + 255) / 256;

    init_kernel<<<nb256, 256, 0, stream>>>(deg, stats1, N, 832);
    degree_kernel<<<ebl, 256, 0, stream>>>(e_col, deg, E);
    scan1_kernel<<<nb256, 256, 0, stream>>>(deg, dinv, offs, bsums, N);
    scan2_kernel<<<1, 512, 0, stream>>>(bsums, nb256);
    scan3_kernel<<<nb256, 256, 0, stream>>>(offs, bsums, cursor, N);
    fill_kernel<<<ebl, 256, 0, stream>>>(e_row, e_col, cursor, csr, E);

    // Layer 1: x(64) -> 128
    gemm_kernel<64, 128><<<(N + 31) / 32, 256, 0, stream>>>(x, W1, dinv, U, N);
    agg_kernel<128><<<(N + 7) / 8, 256, 0, stream>>>(U, csr, offs, deg, dinv, b1, H, N);
    stats_kernel<128><<<512, 256, 0, stream>>>(H, stats1, N);
    norm_kernel<128><<<1024, 256, 0, stream>>>(H, stats1, g1, be1, N);

    // Layer 2: 128 -> 128
    gemm_kernel<128, 128><<<(N + 31) / 32, 256, 0, stream>>>(H, W2, dinv, U, N);
    agg_kernel<128><<<(N + 7) / 8, 256, 0, stream>>>(U, csr, offs, deg, dinv, b2, H, N);
    stats_kernel<128><<<512, 256, 0, stream>>>(H, stats2, N);
    norm_kernel<128><<<1024, 256, 0, stream>>>(H, stats2, g2, be2, N);

    // Layer 3: 128 -> 64
    gemm_kernel<128, 64><<<(N + 63) / 64, 256, 0, stream>>>(H, W3, dinv, U, N);
    agg_kernel<64><<<(N + 15) / 16, 256, 0, stream>>>(U, csr, offs, deg, dinv, b3, H, N);
    stats_kernel<64><<<512, 256, 0, stream>>>(H, stats3, N);
    norm_pool_kernel<<<1024, 256, 0, stream>>>(H, x, stats3, g3, be3, pool, N);

    // Head MLP
    mlp_kernel<<<1, 128, 0, stream>>>(pool, fc1w, fc1b, fc2w, fc2b, fc3w, fc3b,
                                      fc4w, fc4b, (float*)d_out, N);
}

// Round 2
// 755.606 us; speedup vs baseline: 1.2357x; 1.2357x over previous
//
#include <hip/hip_runtime.h>
#include <hip/hip_bf16.h>
#include <math.h>

// GNN: 3-layer GCN + BN + GELU + residual + meanpool + MLP -> scalar.
// R2: layer-1 aggregates BEFORE the GEMM (64-dim gather, halves traffic, kills
// U1 roundtrip); gather loop unrolled x4 (MLP); BN+GELU fused into next GEMM's
// LDS staging (norm passes deleted); register-blocked fp32 GEMM.

__device__ __forceinline__ float gelu_f(float x) {
    return 0.5f * x * (1.0f + erff(x * 0.7071067811865476f));
}

__device__ __forceinline__ int wave_incl_scan(int v, int lane) {
#pragma unroll
    for (int off = 1; off < 64; off <<= 1) {
        int t = __shfl_up(v, (unsigned)off, 64);
        if (lane >= off) v += t;
    }
    return v;
}

// ---- init: deg = 1.0 (self loop), zero double accumulators ----
__global__ void init_kernel(float* __restrict__ deg, double* __restrict__ dbls,
                            int n, int ndbl) {
    int i = blockIdx.x * 256 + threadIdx.x;
    if (i < n) deg[i] = 1.0f;
    if (i < ndbl) dbls[i] = 0.0;
}

__global__ void degree_kernel(const int* __restrict__ col, float* __restrict__ deg, int E) {
    int e = blockIdx.x * 256 + threadIdx.x;
    if (e < E) atomicAdd(&deg[col[e]], 1.0f);
}

__global__ __launch_bounds__(256) void scan1_kernel(const float* __restrict__ deg,
                                                    float* __restrict__ dinv,
                                                    int* __restrict__ offs,
                                                    int* __restrict__ bsums, int n) {
    int i = blockIdx.x * 256 + threadIdx.x;
    int lane = threadIdx.x & 63;
    int wid = threadIdx.x >> 6;
    int cnt = 0;
    if (i < n) {
        float d = deg[i];
        dinv[i] = 1.0f / sqrtf(d);
        cnt = (int)d - 1;
    }
    int incl = wave_incl_scan(cnt, lane);
    __shared__ int ws[4];
    if (lane == 63) ws[wid] = incl;
    __syncthreads();
    if (threadIdx.x == 0) {
        int a = 0;
#pragma unroll
        for (int j = 0; j < 4; j++) { int t = ws[j]; ws[j] = a; a += t; }
        bsums[blockIdx.x] = a;
    }
    __syncthreads();
    int excl = incl - cnt + ws[wid];
    if (i < n) offs[i] = excl;
}

__global__ __launch_bounds__(512) void scan2_kernel(int* __restrict__ bsums, int nblk) {
    int lane = threadIdx.x & 63;
    int wid = threadIdx.x >> 6;
    int v = (threadIdx.x < nblk) ? bsums[threadIdx.x] : 0;
    int incl = wave_incl_scan(v, lane);
    __shared__ int ws[8];
    if (lane == 63) ws[wid] = incl;
    __syncthreads();
    if (threadIdx.x == 0) {
        int a = 0;
#pragma unroll
        for (int j = 0; j < 8; j++) { int t = ws[j]; ws[j] = a; a += t; }
    }
    __syncthreads();
    int excl = incl - v + ws[wid];
    if (threadIdx.x < nblk) bsums[threadIdx.x] = excl;
}

__global__ void scan3_kernel(int* __restrict__ offs, const int* __restrict__ bsums,
                             int* __restrict__ cursor, int n) {
    int i = blockIdx.x * 256 + threadIdx.x;
    if (i < n) {
        int o = offs[i] + bsums[i >> 8];
        offs[i] = o;
        cursor[i] = o;
    }
}

__global__ void fill_kernel(const int* __restrict__ row, const int* __restrict__ col,
                            int* __restrict__ cursor, int* __restrict__ csr, int E) {
    int e = blockIdx.x * 256 + threadIdx.x;
    if (e < E) {
        int c = col[e];
        int pos = atomicAdd(&cursor[c], 1);
        csr[pos] = row[e];
    }
}

// ---- aggregation over in-edges + self loop, x4 unrolled gather ----
// PRE=true : Out[i] = dinv_i * (dinv_i*U_i + sum_j dinv_j*U_j)         (no bias)
// PRE=false: Out[i] = dinv_i * (U_i + sum_j U_j) + bias                (U pre-scaled)
template <int D, bool PRE>
__global__ __launch_bounds__(256) void agg_kernel(const float* __restrict__ U,
                                                  const int* __restrict__ csr,
                                                  const int* __restrict__ offs,
                                                  const float* __restrict__ deg,
                                                  const float* __restrict__ dinv,
                                                  const float* __restrict__ bias,
                                                  float* __restrict__ Out, int n) {
    constexpr int GPN = D / 4;
    constexpr int NPB = 256 / GPN;
    int g = threadIdx.x / GPN;
    int cl = threadIdx.x % GPN;
    int node = blockIdx.x * NPB + g;
    if (node >= n) return;
    int c4 = cl * 4;

    float dvi = dinv[node];
    float4 self = *(const float4*)(U + (size_t)node * D + c4);
    float4 a0, a1;
    if (PRE) {
        a0.x = self.x * dvi; a0.y = self.y * dvi;
        a0.z = self.z * dvi; a0.w = self.w * dvi;
    } else {
        a0 = self;
    }
    a1.x = a1.y = a1.z = a1.w = 0.0f;

    int start = offs[node];
    int cnt = (int)deg[node] - 1;
    int j = 0;
    for (; j + 4 <= cnt; j += 4) {
        int s0 = csr[start + j];
        int s1 = csr[start + j + 1];
        int s2 = csr[start + j + 2];
        int s3 = csr[start + j + 3];
        float4 v0 = *(const float4*)(U + (size_t)s0 * D + c4);
        float4 v1 = *(const float4*)(U + (size_t)s1 * D + c4);
        float4 v2 = *(const float4*)(U + (size_t)s2 * D + c4);
        float4 v3 = *(const float4*)(U + (size_t)s3 * D + c4);
        if (PRE) {
            float d0 = dinv[s0], d1 = dinv[s1], d2 = dinv[s2], d3 = dinv[s3];
            v0.x *= d0; v0.y *= d0; v0.z *= d0; v0.w *= d0;
            v1.x *= d1; v1.y *= d1; v1.z *= d1; v1.w *= d1;
            v2.x *= d2; v2.y *= d2; v2.z *= d2; v2.w *= d2;
            v3.x *= d3; v3.y *= d3; v3.z *= d3; v3.w *= d3;
        }
        a0.x += v0.x; a0.y += v0.y; a0.z += v0.z; a0.w += v0.w;
        a1.x += v1.x; a1.y += v1.y; a1.z += v1.z; a1.w += v1.w;
        a0.x += v2.x; a0.y += v2.y; a0.z += v2.z; a0.w += v2.w;
        a1.x += v3.x; a1.y += v3.y; a1.z += v3.z; a1.w += v3.w;
    }
    for (; j < cnt; j++) {
        int s = csr[start + j];
        float4 v = *(const float4*)(U + (size_t)s * D + c4);
        if (PRE) {
            float d = dinv[s];
            v.x *= d; v.y *= d; v.z *= d; v.w *= d;
        }
        a0.x += v.x; a0.y += v.y; a0.z += v.z; a0.w += v.w;
    }
    float4 acc;
    acc.x = a0.x + a1.x; acc.y = a0.y + a1.y;
    acc.z = a0.z + a1.z; acc.w = a0.w + a1.w;

    float4 r;
    if (PRE) {
        r.x = acc.x * dvi; r.y = acc.y * dvi;
        r.z = acc.z * dvi; r.w = acc.w * dvi;
    } else {
        float4 b4 = *(const float4*)(bias + c4);
        r.x = fmaf(acc.x, dvi, b4.x);
        r.y = fmaf(acc.y, dvi, b4.y);
        r.z = fmaf(acc.z, dvi, b4.z);
        r.w = fmaf(acc.w, dvi, b4.w);
    }
    *(float4*)(Out + (size_t)node * D + c4) = r;
}

// ---- register-blocked GEMM: Out[n][DOUT] = f(Hin)[n][DIN] @ W (+bias)(*dinv) ----
// BNIN: apply per-channel scale/shift + GELU to Hin while staging to LDS.
template <int DIN, int DOUT, bool BNIN, bool BIAS, bool DINVOUT>
__global__ __launch_bounds__(256) void gemm_kernel(const float* __restrict__ Hin,
                                                   const float* __restrict__ W,
                                                   const float* __restrict__ scale,
                                                   const float* __restrict__ shift,
                                                   const float* __restrict__ bias,
                                                   const float* __restrict__ dinv,
                                                   float* __restrict__ Out, int n) {
    constexpr int BNODES = 64;
    constexpr int KT = 32;
    constexpr int HP = DIN + 4;        // padded LDS row (breaks bank conflicts)
    constexpr int VC = DOUT / 16;      // cols per thread (8 or 4)
    constexpr int C4 = VC / 4;
    __shared__ float Hs[BNODES * HP];
    __shared__ float Ws[KT * DOUT];

    int node0 = blockIdx.x * BNODES;
    int nv = n - node0;
    if (nv > BNODES) nv = BNODES;
    int cg = threadIdx.x & 15;         // col group: 16 groups x VC cols
    int ng = threadIdx.x >> 4;         // node group: 16 groups x 4 nodes

    // stage H tile (optionally BN+GELU, each element exactly once)
    constexpr int F4 = BNODES * (DIN / 4);
    for (int f = threadIdx.x; f < F4; f += 256) {
        int nn = f / (DIN / 4);
        int k4 = f - nn * (DIN / 4);
        float4 v = make_float4(0.f, 0.f, 0.f, 0.f);
        if (nn < nv)
            v = *(const float4*)(Hin + (size_t)(node0 + nn) * DIN + k4 * 4);
        if (BNIN) {
            float4 sc = *(const float4*)(scale + k4 * 4);
            float4 sh = *(const float4*)(shift + k4 * 4);
            v.x = gelu_f(fmaf(v.x, sc.x, sh.x));
            v.y = gelu_f(fmaf(v.y, sc.y, sh.y));
            v.z = gelu_f(fmaf(v.z, sc.z, sh.z));
            v.w = gelu_f(fmaf(v.w, sc.w, sh.w));
        }
        *(float4*)(Hs + nn * HP + k4 * 4) = v;
    }

    float acc[4][VC];
#pragma unroll
    for (int i = 0; i < 4; i++)
#pragma unroll
        for (int c = 0; c < VC; c++) acc[i][c] = 0.0f;

    for (int kb = 0; kb < DIN; kb += KT) {
        __syncthreads();  // Hs ready (1st iter) / previous Ws consumed
        for (int f = threadIdx.x; f < KT * DOUT / 4; f += 256)
            *(float4*)(Ws + f * 4) = *(const float4*)(W + (size_t)kb * DOUT + f * 4);
        __syncthreads();
#pragma unroll
        for (int kk = 0; kk < KT; kk++) {
            float h[4];
#pragma unroll
            for (int i = 0; i < 4; i++)
                h[i] = Hs[(ng * 4 + i) * HP + kb + kk];
            float w[VC];
#pragma unroll
            for (int c = 0; c < C4; c++) {
                float4 w4 = *(const float4*)(Ws + kk * DOUT + cg * VC + c * 4);
                w[c * 4 + 0] = w4.x; w[c * 4 + 1] = w4.y;
                w[c * 4 + 2] = w4.z; w[c * 4 + 3] = w4.w;
            }
#pragma unroll
            for (int i = 0; i < 4; i++)
#pragma unroll
                for (int c = 0; c < VC; c++)
                    acc[i][c] = fmaf(h[i], w[c], acc[i][c]);
        }
    }

#pragma unroll
    for (int i = 0; i < 4; i++) {
        int nn = ng * 4 + i;
        if (nn < nv) {
            int node = node0 + nn;
            float dv = DINVOUT ? dinv[node] : 1.0f;
#pragma unroll
            for (int c = 0; c < C4; c++) {
                float4 r;
                r.x = acc[i][c * 4 + 0] * dv;
                r.y = acc[i][c * 4 + 1] * dv;
                r.z = acc[i][c * 4 + 2] * dv;
                r.w = acc[i][c * 4 + 3] * dv;
                if (BIAS) {
                    float4 b4 = *(const float4*)(bias + cg * VC + c * 4);
                    r.x += b4.x; r.y += b4.y; r.z += b4.z; r.w += b4.w;
                }
                *(float4*)(Out + (size_t)node * DOUT + cg * VC + c * 4) = r;
            }
        }
    }
}

// ---- BN stats: per-channel sum and sumsq (double) ----
template <int D>
__global__ __launch_bounds__(256) void stats_kernel(const float* __restrict__ X,
                                                    double* __restrict__ stats, int n) {
    constexpr int RPB = 256 / D;
    int c = threadIdx.x % D;
    int r0 = threadIdx.x / D;
    double s = 0.0, s2 = 0.0;
    int rowsPerGrid = gridDim.x * RPB;
    for (int r = blockIdx.x * RPB + r0; r < n; r += rowsPerGrid) {
        float v = X[(size_t)r * D + c];
        s += v;
        s2 += (double)v * (double)v;
    }
    __shared__ double sh[256];
    __shared__ double sh2[256];
    sh[threadIdx.x] = s;
    sh2[threadIdx.x] = s2;
    __syncthreads();
    if (threadIdx.x < D) {
#pragma unroll
        for (int j = 1; j < RPB; j++) {
            s += sh[threadIdx.x + j * D];
            s2 += sh2[threadIdx.x + j * D];
        }
        atomicAdd(&stats[c], s);
        atomicAdd(&stats[c + D], s2);
    }
}

// ---- stats sums -> per-channel scale/shift floats ----
template <int D>
__global__ void finalize_kernel(const double* __restrict__ stats,
                                const float* __restrict__ g, const float* __restrict__ be,
                                float* __restrict__ scale, float* __restrict__ shift, int n) {
    int c = threadIdx.x;
    if (c < D) {
        double mu = stats[c] / n;
        double var = stats[c + D] / n - mu * mu;
        double inv = 1.0 / sqrt(var + 1e-5);
        double sc = (double)g[c] * inv;
        scale[c] = (float)sc;
        shift[c] = (float)((double)be[c] - mu * sc);
    }
}

// ---- layer-3: BN normalize + GELU + residual(x) + mean-pool accumulate ----
__global__ __launch_bounds__(256) void norm_pool_kernel(const float* __restrict__ X3,
                                                        const float* __restrict__ x0,
                                                        const double* __restrict__ stats,
                                                        const float* __restrict__ gw,
                                                        const float* __restrict__ be,
                                                        double* __restrict__ pool, int n) {
    constexpr int D = 64;
    constexpr int RPB = 4;
    int c = threadIdx.x % D;
    double mu = stats[c] / n;
    double var = stats[c + D] / n - mu * mu;
    double inv = 1.0 / sqrt(var + 1e-5);
    float scale = (float)((double)gw[c] * inv);
    float shift = (float)((double)be[c] - mu * (double)gw[c] * inv);
    int r0 = threadIdx.x / D;
    int rowsPerGrid = gridDim.x * RPB;
    double s = 0.0;
    for (int r = blockIdx.x * RPB + r0; r < n; r += rowsPerGrid) {
        size_t idx = (size_t)r * D + c;
        float t = fmaf(X3[idx], scale, shift);
        float res = x0[idx] + gelu_f(t);
        s += res;
    }
    __shared__ double sh[256];
    sh[threadIdx.x] = s;
    __syncthreads();
    if (threadIdx.x < D) {
#pragma unroll
        for (int j = 1; j < RPB; j++) s += sh[threadIdx.x + j * D];
        atomicAdd(&pool[c], s);
    }
}

// ---- head MLP: 64 ->128 ->64 ->32 ->1, single block ----
__global__ __launch_bounds__(128) void mlp_kernel(const double* __restrict__ pool,
                                                  const float* __restrict__ w1, const float* __restrict__ b1,
                                                  const float* __restrict__ w2, const float* __restrict__ b2,
                                                  const float* __restrict__ w3, const float* __restrict__ b3,
                                                  const float* __restrict__ w4, const float* __restrict__ b4,
                                                  float* __restrict__ out, int n) {
    __shared__ float v0[64], h1[128], h2[64], h3[32];
    int t = threadIdx.x;
    if (t < 64) v0[t] = (float)(pool[t] / (double)n);
    __syncthreads();
    if (t < 128) {
        float a = b1[t];
        for (int k = 0; k < 64; k++) a = fmaf(v0[k], w1[k * 128 + t], a);
        h1[t] = gelu_f(a);
    }
    __syncthreads();
    if (t < 64) {
        float a = b2[t];
        for (int k = 0; k < 128; k++) a = fmaf(h1[k], w2[k * 64 + t], a);
        h2[t] = gelu_f(a);
    }
    __syncthreads();
    if (t < 32) {
        float a = b3[t];
        for (int k = 0; k < 64; k++) a = fmaf(h2[k], w3[k * 32 + t], a);
        h3[t] = gelu_f(a);
    }
    __syncthreads();
    if (t == 0) {
        float a = b4[0];
        for (int k = 0; k < 32; k++) a = fmaf(h3[k], w4[k], a);
        out[0] = a;
    }
}

extern "C" void kernel_launch(void* const* d_in, const int* in_sizes, int n_in,
                              void* d_out, int out_size, void* d_ws, size_t ws_size,
                              hipStream_t stream) {
    const float* x    = (const float*)d_in[0];
    const int*   ei   = (const int*)d_in[1];
    const float* W1   = (const float*)d_in[2];
    const float* b1   = (const float*)d_in[3];
    const float* g1   = (const float*)d_in[4];
    const float* be1  = (const float*)d_in[5];
    const float* W2   = (const float*)d_in[6];
    const float* b2   = (const float*)d_in[7];
    const float* g2   = (const float*)d_in[8];
    const float* be2  = (const float*)d_in[9];
    const float* W3   = (const float*)d_in[10];
    const float* b3   = (const float*)d_in[11];
    const float* g3   = (const float*)d_in[12];
    const float* be3  = (const float*)d_in[13];
    const float* fc1w = (const float*)d_in[14];
    const float* fc1b = (const float*)d_in[15];
    const float* fc2w = (const float*)d_in[16];
    const float* fc2b = (const float*)d_in[17];
    const float* fc3w = (const float*)d_in[18];
    const float* fc3b = (const float*)d_in[19];
    const float* fc4w = (const float*)d_in[20];
    const float* fc4b = (const float*)d_in[21];

    const int N = in_sizes[0] / 64;
    const int E = in_sizes[1] / 2;
    const int* e_row = ei;       // source
    const int* e_col = ei + E;   // target (aggregation index)

    // ---- workspace layout ----
    char* ws = (char*)d_ws;
    size_t off = 0;
    double* stats1 = (double*)(ws + off); off += 256 * sizeof(double);
    double* stats2 = (double*)(ws + off); off += 256 * sizeof(double);
    double* stats3 = (double*)(ws + off); off += 256 * sizeof(double);
    double* pool   = (double*)(ws + off); off += 64 * sizeof(double);
    float* scale1 = (float*)(ws + off); off += 128 * sizeof(float);
    float* shift1 = (float*)(ws + off); off += 128 * sizeof(float);
    float* scale2 = (float*)(ws + off); off += 128 * sizeof(float);
    float* shift2 = (float*)(ws + off); off += 128 * sizeof(float);
    float* deg   = (float*)(ws + off); off += (size_t)N * sizeof(float);
    float* dinv  = (float*)(ws + off); off += (size_t)N * sizeof(float);
    off = (off + 15) & ~(size_t)15;
    int* offs    = (int*)(ws + off); off += (size_t)N * sizeof(int);
    int* cursor  = (int*)(ws + off); off += (size_t)N * sizeof(int);
    int* bsums   = (int*)(ws + off); off += 512 * sizeof(int);
    int* csr     = (int*)(ws + off); off += (size_t)E * sizeof(int);
    off = (off + 15) & ~(size_t)15;
    float* U     = (float*)(ws + off); off += (size_t)N * 128 * sizeof(float);
    float* H     = (float*)(ws + off); off += (size_t)N * 128 * sizeof(float);
    // A1 (N x 64) aliases U: consumed by gemm1 before gemm2 overwrites U.

    const int nb256 = (N + 255) / 256;
    const int ebl = (E + 255) / 256;

    init_kernel<<<nb256, 256, 0, stream>>>(deg, stats1, N, 832);
    degree_kernel<<<ebl, 256, 0, stream>>>(e_col, deg, E);
    scan1_kernel<<<nb256, 256, 0, stream>>>(deg, dinv, offs, bsums, N);
    scan2_kernel<<<1, 512, 0, stream>>>(bsums, nb256);
    scan3_kernel<<<nb256, 256, 0, stream>>>(offs, bsums, cursor, N);
    fill_kernel<<<ebl, 256, 0, stream>>>(e_row, e_col, cursor, csr, E);

    // Layer 1: aggregate x in 64-dim FIRST, then GEMM (+b1) -> H1
    agg_kernel<64, true><<<(N + 15) / 16, 256, 0, stream>>>(
        x, csr, offs, deg, dinv, nullptr, U, N);              // A1 in U
    gemm_kernel<64, 128, false, true, false><<<(N + 63) / 64, 256, 0, stream>>>(
        U, W1, nullptr, nullptr, b1, dinv, H, N);             // H1
    stats_kernel<128><<<512, 256, 0, stream>>>(H, stats1, N);
    finalize_kernel<128><<<1, 128, 0, stream>>>(stats1, g1, be1, scale1, shift1, N);

    // Layer 2: GEMM (BN1+GELU fused on input) -> U2, aggregate -> H2
    gemm_kernel<128, 128, true, false, true><<<(N + 63) / 64, 256, 0, stream>>>(
        H, W2, scale1, shift1, nullptr, dinv, U, N);          // U2 (overwrites A1)
    agg_kernel<128, false><<<(N + 7) / 8, 256, 0, stream>>>(
        U, csr, offs, deg, dinv, b2, H, N);                   // H2
    stats_kernel<128><<<512, 256, 0, stream>>>(H, stats2, N);
    finalize_kernel<128><<<1, 128, 0, stream>>>(stats2, g2, be2, scale2, shift2, N);

    // Layer 3: GEMM (BN2+GELU fused) 128->64 -> U3, aggregate -> H3
    gemm_kernel<128, 64, true, false, true><<<(N + 63) / 64, 256, 0, stream>>>(
        H, W3, scale2, shift2, nullptr, dinv, U, N);          // U3 (N x 64)
    agg_kernel<64, false><<<(N + 15) / 16, 256, 0, stream>>>(
        U, csr, offs, deg, dinv, b3, H, N);                   // H3 (N x 64)
    stats_kernel<64><<<512, 256, 0, stream>>>(H, stats3, N);
    norm_pool_kernel<<<1024, 256, 0, stream>>>(H, x, stats3, g3, be3, pool, N);

    // Head MLP
    mlp_kernel<<<1, 128, 0, stream>>>(pool, fc1w, fc1b, fc2w, fc2b, fc3w, fc3b,
                                      fc4w, fc4b, (float*)d_out, N);
}